// Round 4
// baseline (170.498 us; speedup 1.0000x reference)
//
#include <hip/hip_runtime.h>
#include <stdint.h>

#define SEQ 4096
#define DIMK 2048
#define HD 256

typedef __attribute__((ext_vector_type(8))) short bf16x8;
typedef __attribute__((ext_vector_type(4))) short u16x4;
typedef __attribute__((ext_vector_type(4))) float f32x4;
typedef unsigned short u16;
typedef unsigned int u32;

__device__ __forceinline__ u16 f2bf(float f) {
    u32 u = __float_as_uint(f);
    u += 0x7FFFu + ((u >> 16) & 1u);   // round-to-nearest-even
    return (u16)(u >> 16);
}

__device__ __forceinline__ bf16x8 pack8(f32x4 a0, f32x4 a1) {
    bf16x8 v8;
    v8[0]=(short)f2bf(a0[0]); v8[1]=(short)f2bf(a0[1]);
    v8[2]=(short)f2bf(a0[2]); v8[3]=(short)f2bf(a0[3]);
    v8[4]=(short)f2bf(a1[0]); v8[5]=(short)f2bf(a1[1]);
    v8[6]=(short)f2bf(a1[2]); v8[7]=(short)f2bf(a1[3]);
    return v8;
}

// ---------------------------------------------------------------------------
// f32 -> bf16 bulk convert, all 4 tensors in one launch (y: 0=x, 1..3=W)
// ---------------------------------------------------------------------------
__global__ __launch_bounds__(256) void cvt_all(
    const float* __restrict__ x, const float* __restrict__ Wq,
    const float* __restrict__ Wk, const float* __restrict__ Wv,
    u16* __restrict__ xb, u16* __restrict__ wb)
{
    const int y = blockIdx.y;
    const float* src; u16* dst; int n8;
    if (y == 0)      { src = x;  dst = xb;                 n8 = SEQ*DIMK/8; }
    else if (y == 1) { src = Wq; dst = wb;                 n8 = HD*DIMK/8; }
    else if (y == 2) { src = Wk; dst = wb + HD*DIMK;       n8 = HD*DIMK/8; }
    else             { src = Wv; dst = wb + 2*HD*DIMK;     n8 = HD*DIMK/8; }
    int i = blockIdx.x * 256 + threadIdx.x;
    int stride = gridDim.x * 256;
    for (; i < n8; i += stride) {
        f32x4 a0 = *(const f32x4*)(src + (size_t)i*8);
        f32x4 a1 = *(const f32x4*)(src + (size_t)i*8 + 4);
        *(bf16x8*)(dst + (size_t)i*8) = pack8(a0, a1);
    }
}

// ---------------------------------------------------------------------------
// QKV projection from bf16: C[S,768] = xb[S,D] @ wb[768,D]^T + b
// z==0 -> qb row-major (scaled), z==1 -> kb row-major, z==2 -> vtb TRANSPOSED.
// ---------------------------------------------------------------------------
__global__ __launch_bounds__(256) void qkv_gemm_bf16(
    const u16* __restrict__ xb, const u16* __restrict__ wb,
    const float* __restrict__ bq, const float* __restrict__ bk,
    const float* __restrict__ bv,
    u16* __restrict__ qb, u16* __restrict__ kb, u16* __restrict__ vtb)
{
    __shared__ char As[64*128];
    __shared__ char Bs[128*128];

    const int tid  = threadIdx.x;
    const int lane = tid & 63;
    const int w    = tid >> 6;
    const int r    = lane & 15, g = lane >> 4;
    const int wr   = w >> 1, wc = w & 1;
    const int m0   = blockIdx.x * 64;
    const int n0   = blockIdx.y * 128;
    const int z    = blockIdx.y >> 1;
    const float* bias = (z==0) ? bq : (z==1) ? bk : bv;
    const float scale = (z==0) ? 0.02209708691207961f : 1.0f;  // 1/sqrt(2048)

    f32x4 zero = {0.f,0.f,0.f,0.f};
    f32x4 acc[2][4];
    #pragma unroll
    for (int m = 0; m < 2; ++m)
        #pragma unroll
        for (int n = 0; n < 4; ++n) acc[m][n] = zero;

    for (int kt = 0; kt < DIMK/64; ++kt) {
        #pragma unroll
        for (int it = 0; it < 2; ++it) {
            int ch = it*256 + tid;
            int row = ch >> 3, slot = ch & 7;
            bf16x8 v8 = *(const bf16x8*)(xb + (size_t)(m0+row)*DIMK + kt*64 + slot*8);
            *(bf16x8*)(As + row*128 + ((slot ^ (row&7)) << 4)) = v8;
        }
        #pragma unroll
        for (int it = 0; it < 4; ++it) {
            int ch = it*256 + tid;
            int row = ch >> 3, slot = ch & 7;
            bf16x8 v8 = *(const bf16x8*)(wb + (size_t)(n0+row)*DIMK + kt*64 + slot*8);
            *(bf16x8*)(Bs + row*128 + ((slot ^ (row&7)) << 4)) = v8;
        }
        __syncthreads();
        #pragma unroll
        for (int kc = 0; kc < 2; ++kc) {
            bf16x8 af[2], bfr[4];
            #pragma unroll
            for (int m = 0; m < 2; ++m) {
                int arow = wr*32 + m*16 + r;
                af[m] = *(const bf16x8*)(As + arow*128 + (((kc*4+g) ^ (arow&7)) << 4));
            }
            #pragma unroll
            for (int n = 0; n < 4; ++n) {
                int brow = wc*64 + n*16 + r;
                bfr[n] = *(const bf16x8*)(Bs + brow*128 + (((kc*4+g) ^ (brow&7)) << 4));
            }
            #pragma unroll
            for (int m = 0; m < 2; ++m)
                #pragma unroll
                for (int n = 0; n < 4; ++n)
                    acc[m][n] = __builtin_amdgcn_mfma_f32_16x16x32_bf16(
                        af[m], bfr[n], acc[m][n], 0, 0, 0);
        }
        __syncthreads();
    }
    if (z == 2) {
        // transposed store: vtb[hd][row], 4 consecutive rows packed per store
        #pragma unroll
        for (int n = 0; n < 4; ++n) {
            int col = n0 + wc*64 + n*16 + r;
            int hc  = col & 255;
            float bcol = bias[hc];
            #pragma unroll
            for (int m = 0; m < 2; ++m) {
                int row0 = m0 + wr*32 + m*16 + g*4;
                u16x4 pk;
                #pragma unroll
                for (int j = 0; j < 4; ++j) pk[j] = (short)f2bf(acc[m][n][j] + bcol);
                *(u16x4*)(vtb + (size_t)hc*SEQ + row0) = pk;
            }
        }
    } else {
        u16* outp = (z==0) ? qb : kb;
        #pragma unroll
        for (int n = 0; n < 4; ++n) {
            int col = n0 + wc*64 + n*16 + r;
            int hc  = col & 255;
            float bcol = bias[hc];
            #pragma unroll
            for (int m = 0; m < 2; ++m) {
                int row0 = m0 + wr*32 + m*16 + g*4;
                #pragma unroll
                for (int j = 0; j < 4; ++j) {
                    float v = (acc[m][n][j] + bcol) * scale;
                    outp[(size_t)(row0+j)*HD + hc] = f2bf(v);
                }
            }
        }
    }
}

// ---------------------------------------------------------------------------
// Barrier-free flash attention: one WAVE per (q16-block i, kv-split s).
// Band b=i/32 has ns=b+1 splits; unit id u enumerates (i,s).
// K A-frags + V^T A-frags loaded DIRECTLY from global (64B-chunk gathers,
// same L2 line count as coalesced). Only LDS use: per-wave 2.25KB P buffer.
// ---------------------------------------------------------------------------
__global__ __launch_bounds__(256, 3) void attn_part2(
    const u16* __restrict__ qb, const u16* __restrict__ kb,
    const u16* __restrict__ vtb,
    float* __restrict__ po, float* __restrict__ pm, float* __restrict__ pl)
{
    __shared__ char Ps[4 * 16 * 144];

    const int tid  = threadIdx.x;
    const int lane = tid & 63;
    const int w    = tid >> 6;
    const int r    = lane & 15, g = lane >> 4;
    const float LOG2E = 1.4426950408889634f;

    // XCD-chunked block swizzle (gridDim.x = 288, divisible by 8)
    const int nper = gridDim.x >> 3;
    const int ebid = (blockIdx.x & 7) * nper + (blockIdx.x >> 3);
    const int u = ebid * 4 + w;

    // unit -> (band, i, s)
    int b = 0;
    #pragma unroll
    for (int k = 1; k < 8; ++k) if (u >= 16*k*(k+1)) b = k;
    const int ns = b + 1;
    const int off = u - 16*b*(b+1);
    const int io  = off / ns;
    const int s   = off - io*ns;
    const int i   = 32*b + io;
    const int nt  = (i >> 2) + 1;
    const int chunk = (nt + ns - 1) / ns;
    const int t0 = s * chunk;
    const int t1 = min(t0 + chunk, nt);

    char* Psw = Ps + w * (16*144);
    const int qg = i*16 + r;

    // Q B-frags: lane r = q-row, d-slice g*8 + c*32
    bf16x8 qf[8];
    {
        const u16* qp = qb + (size_t)qg * HD + g*8;
        #pragma unroll
        for (int c = 0; c < 8; ++c) qf[c] = *(const bf16x8*)(qp + c*32);
    }

    f32x4 zero = {0.f,0.f,0.f,0.f};
    f32x4 o[16];
    #pragma unroll
    for (int hf = 0; hf < 16; ++hf) o[hf] = zero;
    float mrun = -__builtin_inff(), lrun = 0.f;

    for (int t = t0; t < t1; ++t) {
        // ---- S^T = K Q^T : direct-global K A-frags ----
        f32x4 sv[4];
        const u16* kbase = kb + (size_t)t*64*HD + (size_t)r*HD + g*8;
        __builtin_amdgcn_s_setprio(1);
        #pragma unroll
        for (int f = 0; f < 4; ++f) {
            sv[f] = zero;
            const u16* kp = kbase + (size_t)f*16*HD;
            #pragma unroll
            for (int c = 0; c < 8; ++c) {
                bf16x8 kf = *(const bf16x8*)(kp + c*32);
                sv[f] = __builtin_amdgcn_mfma_f32_16x16x32_bf16(kf, qf[c], sv[f], 0, 0, 0);
            }
        }
        __builtin_amdgcn_s_setprio(0);

        // ---- causal mask: only the final tile straddles the diagonal ----
        if (t == nt - 1) {
            #pragma unroll
            for (int f = 0; f < 4; ++f)
                #pragma unroll
                for (int j = 0; j < 4; ++j) {
                    int kvg = t*64 + f*16 + g*4 + j;
                    if (kvg > qg) sv[f][j] = -__builtin_inff();
                }
        }

        // ---- lane-local online softmax (lane owns full q-row slice) ----
        float mx = -__builtin_inff();
        #pragma unroll
        for (int f = 0; f < 4; ++f)
            #pragma unroll
            for (int j = 0; j < 4; ++j) mx = fmaxf(mx, sv[f][j]);
        mx = fmaxf(mx, __shfl_xor(mx, 16));
        mx = fmaxf(mx, __shfl_xor(mx, 32));
        float mnew  = fmaxf(mrun, mx);
        float alpha = exp2f((mrun - mnew) * LOG2E);
        mrun = mnew;
        float rs = 0.f;
        #pragma unroll
        for (int f = 0; f < 4; ++f)
            #pragma unroll
            for (int j = 0; j < 4; ++j) {
                float p = exp2f((sv[f][j] - mnew) * LOG2E);
                sv[f][j] = p;
                rs += p;
            }
        rs += __shfl_xor(rs, 16);
        rs += __shfl_xor(rs, 32);
        lrun = lrun * alpha + rs;
        #pragma unroll
        for (int hf = 0; hf < 16; ++hf) o[hf] *= alpha;

        // ---- P -> bf16 -> per-wave Ps (wave-local, no barrier) ----
        #pragma unroll
        for (int f = 0; f < 4; ++f)
            #pragma unroll
            for (int pi = 0; pi < 2; ++pi) {
                u32 pk = (u32)f2bf(sv[f][2*pi]) | ((u32)f2bf(sv[f][2*pi+1]) << 16);
                *(u32*)(Psw + r*144 + (f*8 + g*2 + pi)*4) = pk;
            }
        bf16x8 pa0 = *(const bf16x8*)(Psw + r*144 + g*16);
        bf16x8 pa1 = *(const bf16x8*)(Psw + r*144 + 64 + g*16);

        // ---- O^T += V^T P^T : direct-global V^T A-frags ----
        const u16* vbase = vtb + (size_t)r*SEQ + t*64 + g*8;
        __builtin_amdgcn_s_setprio(1);
        #pragma unroll
        for (int hf = 0; hf < 16; ++hf) {
            const u16* vp = vbase + (size_t)hf*16*SEQ;
            bf16x8 vf0 = *(const bf16x8*)(vp);
            bf16x8 vf1 = *(const bf16x8*)(vp + 32);
            o[hf] = __builtin_amdgcn_mfma_f32_16x16x32_bf16(vf0, pa0, o[hf], 0, 0, 0);
            o[hf] = __builtin_amdgcn_mfma_f32_16x16x32_bf16(vf1, pa1, o[hf], 0, 0, 0);
        }
        __builtin_amdgcn_s_setprio(0);
    }

    // ---- epilogue: lane (r,g) holds O[q=r][hd=hf*16+g*4+j]; pid = u ----
    if (g == 0) {
        pm[(size_t)u*16 + r] = mrun;
        pl[(size_t)u*16 + r] = lrun;
    }
    float* op = po + ((size_t)u*16 + r) * 256;
    #pragma unroll
    for (int hf = 0; hf < 16; ++hf)
        *(f32x4*)(op + hf*16 + g*4) = o[hf];
}

// ---------------------------------------------------------------------------
// Combine: one block per q16-block. out = sum_s w_s o_s / sum_s w_s l_s
// ---------------------------------------------------------------------------
__global__ __launch_bounds__(256) void attn_combine2(
    const float* __restrict__ po, const float* __restrict__ pm,
    const float* __restrict__ pl, float* __restrict__ out)
{
    const float LOG2E = 1.4426950408889634f;
    const int i   = blockIdx.x;
    const int b   = i >> 5;
    const int ns  = b + 1;
    const int pid0 = 16*b*(b+1) + (i - 32*b)*ns;
    const int tid = threadIdx.x;
    const int row = tid >> 4;
    const int cg  = tid & 15;

    float M = -__builtin_inff();
    for (int s = 0; s < ns; ++s)
        M = fmaxf(M, pm[(size_t)(pid0+s)*16 + row]);

    float lt = 0.f;
    f32x4 acc[4];
    f32x4 zero = {0.f,0.f,0.f,0.f};
    #pragma unroll
    for (int v = 0; v < 4; ++v) acc[v] = zero;

    for (int s = 0; s < ns; ++s) {
        float ms = pm[(size_t)(pid0+s)*16 + row];
        float wgt = exp2f((ms - M) * LOG2E);
        lt += wgt * pl[(size_t)(pid0+s)*16 + row];
        const f32x4* p = (const f32x4*)(po + ((size_t)(pid0+s)*16 + row)*256 + cg*16);
        #pragma unroll
        for (int v = 0; v < 4; ++v) acc[v] += p[v] * wgt;
    }
    float inv = 1.f / lt;
    f32x4* op = (f32x4*)(out + (size_t)(i*16 + row)*256 + cg*16);
    #pragma unroll
    for (int v = 0; v < 4; ++v) op[v] = acc[v] * inv;
}

// ===========================================================================
// Fallback (round-0 verified kernels) — used only if ws_size is too small.
// ===========================================================================
__global__ __launch_bounds__(256) void qkv_gemm_f32(
    const float* __restrict__ x,
    const float* __restrict__ Wq, const float* __restrict__ bq,
    const float* __restrict__ Wk, const float* __restrict__ bk,
    const float* __restrict__ Wv, const float* __restrict__ bv,
    u16* __restrict__ qb, u16* __restrict__ kb, u16* __restrict__ vb)
{
    const int z = blockIdx.y;
    const float* W    = (z == 0) ? Wq : (z == 1) ? Wk : Wv;
    const float* bias = (z == 0) ? bq : (z == 1) ? bk : bv;
    u16* outp         = (z == 0) ? qb : (z == 1) ? kb : vb;
    const float scale = (z == 0) ? 0.02209708691207961f : 1.0f;

    __shared__ u16 As[64][72];
    __shared__ u16 Bs[HD][72];

    const int tid  = threadIdx.x;
    const int lane = tid & 63;
    const int w    = tid >> 6;
    const int r    = lane & 15, g = lane >> 4;
    const int m0   = blockIdx.x * 64;

    f32x4 zero = {0.f,0.f,0.f,0.f};
    f32x4 acc[4][4];
    #pragma unroll
    for (int m = 0; m < 4; ++m)
        #pragma unroll
        for (int n = 0; n < 4; ++n) acc[m][n] = zero;

    for (int kt = 0; kt < DIMK / 64; ++kt) {
        #pragma unroll
        for (int it = 0; it < 2; ++it) {
            int ch = it * 256 + tid;
            int row = ch >> 3, colc = (ch & 7) * 8;
            const float* src = x + (size_t)(m0 + row) * DIMK + kt * 64 + colc;
            *(bf16x8*)&As[row][colc] = pack8(*(const f32x4*)src, *(const f32x4*)(src+4));
        }
        #pragma unroll
        for (int it = 0; it < 8; ++it) {
            int ch = it * 256 + tid;
            int row = ch >> 3, colc = (ch & 7) * 8;
            const float* src = W + (size_t)row * DIMK + kt * 64 + colc;
            *(bf16x8*)&Bs[row][colc] = pack8(*(const f32x4*)src, *(const f32x4*)(src+4));
        }
        __syncthreads();
        #pragma unroll
        for (int kc = 0; kc < 2; ++kc) {
            bf16x8 af[4], bfr[4];
            #pragma unroll
            for (int m = 0; m < 4; ++m)
                af[m] = *(const bf16x8*)&As[m*16 + r][kc*32 + g*8];
            #pragma unroll
            for (int n = 0; n < 4; ++n)
                bfr[n] = *(const bf16x8*)&Bs[w*64 + n*16 + r][kc*32 + g*8];
            #pragma unroll
            for (int m = 0; m < 4; ++m)
                #pragma unroll
                for (int n = 0; n < 4; ++n)
                    acc[m][n] = __builtin_amdgcn_mfma_f32_16x16x32_bf16(
                        af[m], bfr[n], acc[m][n], 0, 0, 0);
        }
        __syncthreads();
    }
    #pragma unroll
    for (int n = 0; n < 4; ++n) {
        int col = w*64 + n*16 + r;
        float bcol = bias[col];
        #pragma unroll
        for (int m = 0; m < 4; ++m) {
            int row0 = m0 + m*16 + g*4;
            #pragma unroll
            for (int j = 0; j < 4; ++j) {
                float v = (acc[m][n][j] + bcol) * scale;
                outp[(size_t)(row0 + j) * HD + col] = f2bf(v);
            }
        }
    }
}

__global__ __launch_bounds__(256) void attn_fused(
    const u16* __restrict__ qb, const u16* __restrict__ kb,
    const u16* __restrict__ vb, float* __restrict__ out)
{
    __shared__ char Ks[64 * 512];
    __shared__ char Vt[256 * 128];

    const int tid  = threadIdx.x;
    const int lane = tid & 63;
    const int w    = tid >> 6;
    const int r    = lane & 15, g = lane >> 4;
    const int qt   = blockIdx.x;
    const float LOG2E = 1.4426950408889634f;

    char* Ps = Ks + w * 2048;

    bf16x8 qf[8];
    {
        const u16* qp = qb + (size_t)(qt*64 + w*16 + r) * HD + g*8;
        #pragma unroll
        for (int c = 0; c < 8; ++c) qf[c] = *(const bf16x8*)(qp + c*32);
    }

    f32x4 zero = {0.f,0.f,0.f,0.f};
    f32x4 o[16];
    #pragma unroll
    for (int i = 0; i < 16; ++i) o[i] = zero;
    float mrun[4], lrun[4];
    #pragma unroll
    for (int j = 0; j < 4; ++j) { mrun[j] = -__builtin_inff(); lrun[j] = 0.f; }

    const int qrow_l = w*16 + g*4;

    for (int t = 0; t <= qt; ++t) {
        __syncthreads();
        #pragma unroll
        for (int it = 0; it < 8; ++it) {
            int ch = it*256 + tid;
            int row = ch >> 5, colc = (ch & 31) * 8;
            bf16x8 k8 = *(const bf16x8*)(kb + (size_t)(t*64 + row)*HD + colc);
            int slot = (colc >> 3) ^ (row & 7);
            *(bf16x8*)(Ks + row*512 + slot*16) = k8;
        }
        {
            int ht = tid & 31;
            int vt = tid >> 5;
            bf16x8 vin[8];
            #pragma unroll
            for (int i = 0; i < 8; ++i)
                vin[i] = *(const bf16x8*)(vb + (size_t)(t*64 + vt*8 + i)*HD + ht*8);
            #pragma unroll
            for (int j = 0; j < 8; ++j) {
                bf16x8 vo;
                #pragma unroll
                for (int i = 0; i < 8; ++i) vo[i] = vin[i][j];
                int hd = ht*8 + j;
                int slot = vt ^ (hd & 7) ^ ((hd >> 3) & 7);
                *(bf16x8*)(Vt + hd*128 + slot*16) = vo;
            }
        }
        __syncthreads();

        f32x4 sfr[4];
        #pragma unroll
        for (int f = 0; f < 4; ++f) {
            sfr[f] = zero;
            int kv = f*16 + r;
            #pragma unroll
            for (int c = 0; c < 8; ++c) {
                int slot = (c*4 + g) ^ (kv & 7);
                bf16x8 kf = *(const bf16x8*)(Ks + kv*512 + slot*16);
                sfr[f] = __builtin_amdgcn_mfma_f32_16x16x32_bf16(qf[c], kf, sfr[f], 0, 0, 0);
            }
        }
        #pragma unroll
        for (int j = 0; j < 4; ++j) {
            int qg = qt*64 + qrow_l + j;
            #pragma unroll
            for (int f = 0; f < 4; ++f) {
                int kvg = t*64 + f*16 + r;
                if (kvg > qg) sfr[f][j] = -__builtin_inff();
            }
            float mx = fmaxf(fmaxf(sfr[0][j], sfr[1][j]), fmaxf(sfr[2][j], sfr[3][j]));
            mx = fmaxf(mx, __shfl_xor(mx, 1));
            mx = fmaxf(mx, __shfl_xor(mx, 2));
            mx = fmaxf(mx, __shfl_xor(mx, 4));
            mx = fmaxf(mx, __shfl_xor(mx, 8));
            float mnew  = fmaxf(mrun[j], mx);
            float alpha = exp2f((mrun[j] - mnew) * LOG2E);
            mrun[j] = mnew;
            float rs = 0.f;
            #pragma unroll
            for (int f = 0; f < 4; ++f) {
                float p = exp2f((sfr[f][j] - mnew) * LOG2E);
                sfr[f][j] = p;
                rs += p;
            }
            rs += __shfl_xor(rs, 1); rs += __shfl_xor(rs, 2);
            rs += __shfl_xor(rs, 4); rs += __shfl_xor(rs, 8);
            lrun[j] = lrun[j] * alpha + rs;
            #pragma unroll
            for (int hf = 0; hf < 16; ++hf) o[hf][j] *= alpha;
        }
        __syncthreads();

        #pragma unroll
        for (int f = 0; f < 4; ++f) {
            #pragma unroll
            for (int j = 0; j < 4; ++j) {
                int q  = g*4 + j;
                int kv = f*16 + r;
                int byte_off = (kv*2) ^ ((q & 7) << 4);
                *(u16*)(Ps + q*128 + byte_off) = f2bf(sfr[f][j]);
            }
        }
        bf16x8 pa[2];
        #pragma unroll
        for (int ck = 0; ck < 2; ++ck) {
            int slot = (ck*4 + g) ^ (r & 7);
            pa[ck] = *(const bf16x8*)(Ps + r*128 + slot*16);
        }
        #pragma unroll
        for (int hf = 0; hf < 16; ++hf) {
            int hd = hf*16 + r;
            #pragma unroll
            for (int ck = 0; ck < 2; ++ck) {
                int slot = (ck*4 + g) ^ (hd & 7) ^ ((hd >> 3) & 7);
                bf16x8 vf = *(const bf16x8*)(Vt + hd*128 + slot*16);
                o[hf] = __builtin_amdgcn_mfma_f32_16x16x32_bf16(pa[ck], vf, o[hf], 0, 0, 0);
            }
        }
    }

    #pragma unroll
    for (int j = 0; j < 4; ++j) {
        float inv = 1.0f / lrun[j];
        int qg = qt*64 + qrow_l + j;
        float* op = out + (size_t)qg * HD;
        #pragma unroll
        for (int hf = 0; hf < 16; ++hf) op[hf*16 + r] = o[hf][j] * inv;
    }
}

extern "C" void kernel_launch(void* const* d_in, const int* in_sizes, int n_in,
                              void* d_out, int out_size, void* d_ws, size_t ws_size,
                              hipStream_t stream) {
    const float* x  = (const float*)d_in[0];
    const float* Wq = (const float*)d_in[1];
    const float* bq = (const float*)d_in[2];
    const float* Wk = (const float*)d_in[3];
    const float* bk = (const float*)d_in[4];
    const float* Wv = (const float*)d_in[5];
    const float* bv = (const float*)d_in[6];
    float* out = (float*)d_out;

    const size_t xb_bytes  = (size_t)SEQ * DIMK * 2;     // 16 MB
    const size_t wb_bytes  = (size_t)768 * DIMK * 2;     // 3 MB
    const size_t qkv_bytes = (size_t)SEQ * HD * 2;       // 2 MB each
    const size_t NU = 1152;                              // total wave-units
    const size_t po_bytes = NU * 16 * 256 * 4;           // 18.9 MB
    const size_t pml_bytes = NU * 16 * 4;
    const size_t need = xb_bytes + wb_bytes + 3*qkv_bytes + po_bytes + 2*pml_bytes;

    if (need > ws_size) {
        // fallback: round-0 path (needs only 6 MB of ws)
        u16* qbuf = (u16*)d_ws;
        u16* kbuf = qbuf + (size_t)SEQ * HD;
        u16* vbuf = kbuf + (size_t)SEQ * HD;
        qkv_gemm_f32<<<dim3(SEQ/64, 3), 256, 0, stream>>>(
            x, Wq, bq, Wk, bk, Wv, bv, qbuf, kbuf, vbuf);
        attn_fused<<<SEQ/64, 256, 0, stream>>>(qbuf, kbuf, vbuf, out);
        return;
    }

    char* p = (char*)d_ws;
    u16* xb   = (u16*)p; p += xb_bytes;
    u16* wb   = (u16*)p; p += wb_bytes;
    u16* qbuf = (u16*)p; p += qkv_bytes;
    u16* kbuf = (u16*)p; p += qkv_bytes;
    u16* vtb  = (u16*)p; p += qkv_bytes;   // TRANSPOSED V [HD][SEQ]
    float* po = (float*)p; p += po_bytes;
    float* pm = (float*)p; p += pml_bytes;
    float* pl = (float*)p; p += pml_bytes;

    cvt_all<<<dim3(512, 4), 256, 0, stream>>>(x, Wq, Wk, Wv, xb, wb);

    qkv_gemm_bf16<<<dim3(SEQ/64, 6), 256, 0, stream>>>(
        xb, wb, bq, bk, bv, qbuf, kbuf, vtb);

    attn_part2<<<288, 256, 0, stream>>>(qbuf, kbuf, vtb, po, pm, pl);

    attn_combine2<<<256, 256, 0, stream>>>(po, pm, pl, out);
}

// Round 5
// 89.420 us; speedup vs baseline: 1.9067x; 1.9067x over previous
//
#include <hip/hip_runtime.h>
#include <stdint.h>

#define SEQ 4096
#define DIMK 2048
#define HD 256

typedef __attribute__((ext_vector_type(8))) short bf16x8;
typedef __attribute__((ext_vector_type(4))) short u16x4;
typedef __attribute__((ext_vector_type(4))) float f32x4;
typedef unsigned short u16;
typedef unsigned int u32;

#define BAR() asm volatile("s_barrier" ::: "memory")
#define VMCNT(n) asm volatile("s_waitcnt vmcnt(" #n ")" ::: "memory")

__device__ __forceinline__ u16 f2bf(float f) {
    u32 u = __float_as_uint(f);
    u += 0x7FFFu + ((u >> 16) & 1u);   // round-to-nearest-even
    return (u16)(u >> 16);
}

__device__ __forceinline__ bf16x8 pack8(f32x4 a0, f32x4 a1) {
    bf16x8 v8;
    v8[0]=(short)f2bf(a0[0]); v8[1]=(short)f2bf(a0[1]);
    v8[2]=(short)f2bf(a0[2]); v8[3]=(short)f2bf(a0[3]);
    v8[4]=(short)f2bf(a1[0]); v8[5]=(short)f2bf(a1[1]);
    v8[6]=(short)f2bf(a1[2]); v8[7]=(short)f2bf(a1[3]);
    return v8;
}

// async global->LDS, 16B per lane, LDS dest = uniform base + lane*16
__device__ __forceinline__ void gl16(const void* g, void* l) {
    __builtin_amdgcn_global_load_lds(
        (const __attribute__((address_space(1))) void*)g,
        (__attribute__((address_space(3))) void*)l, 16, 0, 0);
}

// ---------------------------------------------------------------------------
// f32 -> bf16 convert INTO PRE-SWIZZLED GEMM TILE IMAGES.
// x  -> xb_sw : per (mt,kt) 64x64 tile, 8KB: rl*64u16 + ((slot^(rl&7))*8u16)
// W* -> wb_sw : per (nt,kt) 128x64 tile, 16KB: same swizzle with rl=row&127
// ---------------------------------------------------------------------------
__global__ __launch_bounds__(256) void cvt_all2(
    const float* __restrict__ x, const float* __restrict__ Wq,
    const float* __restrict__ Wk, const float* __restrict__ Wv,
    u16* __restrict__ xb_sw, u16* __restrict__ wb_sw)
{
    const int y = blockIdx.y;
    int i = blockIdx.x * 256 + threadIdx.x;
    int stride = gridDim.x * 256;
    if (y == 0) {
        for (; i < SEQ*DIMK/8; i += stride) {
            int row = i >> 8, c8 = i & 255;
            f32x4 a0 = *(const f32x4*)(x + (size_t)row*DIMK + c8*8);
            f32x4 a1 = *(const f32x4*)(x + (size_t)row*DIMK + c8*8 + 4);
            int mt = row >> 6, rl = row & 63, kt = c8 >> 3, sl = c8 & 7;
            size_t dst = ((size_t)(mt*32 + kt))*4096 + rl*64 + ((sl ^ (rl&7))*8);
            *(bf16x8*)(xb_sw + dst) = pack8(a0, a1);
        }
    } else {
        const float* W = (y==1) ? Wq : (y==2) ? Wk : Wv;
        for (; i < HD*DIMK/8; i += stride) {
            int row = i >> 8, c8 = i & 255;
            f32x4 a0 = *(const f32x4*)(W + (size_t)row*DIMK + c8*8);
            f32x4 a1 = *(const f32x4*)(W + (size_t)row*DIMK + c8*8 + 4);
            int gr = (y-1)*256 + row;
            int nt = gr >> 7, rl = gr & 127, kt = c8 >> 3, sl = c8 & 7;
            size_t dst = ((size_t)(nt*32 + kt))*8192 + rl*64 + ((sl ^ (rl&7))*8);
            *(bf16x8*)(wb_sw + dst) = pack8(a0, a1);
        }
    }
}

// ---------------------------------------------------------------------------
// QKV GEMM: gload_lds staging from swizzled images, double-buffered,
// counted vmcnt(6). BM=64,BN=128,BK=64, 4 waves. Outputs:
//   z=0: qb row-major, scaled by log2(e)/sqrt(2048)
//   z=1: kb_t  = per-32kv-tile [32][512B] swizzled K image
//   z=2: vt_t  = per-32kv-tile [256hd][64B] swizzled V^T image
// ---------------------------------------------------------------------------
__global__ __launch_bounds__(256) void qkv_gemm2(
    const u16* __restrict__ xb_sw, const u16* __restrict__ wb_sw,
    const float* __restrict__ bq, const float* __restrict__ bk,
    const float* __restrict__ bv,
    u16* __restrict__ qb, u16* __restrict__ kb_t, u16* __restrict__ vt_t)
{
    __shared__ char T[2][24576];   // A 8KB @ +0, B 16KB @ +8192

    const int tid = threadIdx.x;
    const int lane = tid & 63;
    const int w = tid >> 6;
    const int r = lane & 15, g = lane >> 4;
    const int wr = w >> 1, wc = w & 1;
    const int mt = blockIdx.x;
    const int y  = blockIdx.y;          // 0..5
    const int z  = y >> 1;
    const float* bias = (z==0) ? bq : (z==1) ? bk : bv;

    const u16* abase = xb_sw + (size_t)mt*32*4096;
    const u16* bbase = wb_sw + (size_t)y*32*8192;

    f32x4 zero = {0.f,0.f,0.f,0.f};
    f32x4 acc[2][4];
    #pragma unroll
    for (int m = 0; m < 2; ++m)
        #pragma unroll
        for (int n = 0; n < 4; ++n) acc[m][n] = zero;

    auto stage = [&](int b, int kt) {
        const u16* ag = abase + (size_t)kt*4096 + w*1024 + lane*8;
        const u16* bg = bbase + (size_t)kt*8192 + w*2048 + lane*8;
        char* al = T[b] + w*2048;
        char* bl = T[b] + 8192 + w*4096;
        gl16(ag,        al);
        gl16(ag + 512,  al + 1024);
        gl16(bg,        bl);
        gl16(bg + 512,  bl + 1024);
        gl16(bg + 1024, bl + 2048);
        gl16(bg + 1536, bl + 3072);
    };

    stage(0, 0);
    stage(1, 1);

    for (int kt = 0; kt < 32; ++kt) {
        if (kt < 31) { VMCNT(6); } else { VMCNT(0); }
        BAR();
        const char* A = T[kt & 1];
        const char* B = T[kt & 1] + 8192;
        #pragma unroll
        for (int kc = 0; kc < 2; ++kc) {
            bf16x8 af[2], bfr[4];
            #pragma unroll
            for (int m = 0; m < 2; ++m) {
                int arow = wr*32 + m*16 + r;
                af[m] = *(const bf16x8*)(A + arow*128 + (((kc*4+g) ^ (arow&7)) << 4));
            }
            #pragma unroll
            for (int n = 0; n < 4; ++n) {
                int brow = wc*64 + n*16 + r;
                bfr[n] = *(const bf16x8*)(B + brow*128 + (((kc*4+g) ^ (brow&7)) << 4));
            }
            #pragma unroll
            for (int m = 0; m < 2; ++m)
                #pragma unroll
                for (int n = 0; n < 4; ++n)
                    acc[m][n] = __builtin_amdgcn_mfma_f32_16x16x32_bf16(
                        af[m], bfr[n], acc[m][n], 0, 0, 0);
        }
        BAR();
        if (kt + 2 < 32) stage(kt & 1, kt + 2);
    }

    const int m0 = mt*64, n0 = y*128;
    const float qs = 0.03187936f;   // log2(e)/sqrt(2048)
    if (z == 0) {
        #pragma unroll
        for (int n = 0; n < 4; ++n) {
            int hc = (n0 + wc*64 + n*16 + r) & 255;
            float bcol = bias[hc];
            #pragma unroll
            for (int m = 0; m < 2; ++m) {
                int row0 = m0 + wr*32 + m*16 + g*4;
                #pragma unroll
                for (int j = 0; j < 4; ++j)
                    qb[(size_t)(row0+j)*HD + hc] = f2bf((acc[m][n][j] + bcol) * qs);
            }
        }
    } else if (z == 1) {
        #pragma unroll
        for (int n = 0; n < 4; ++n) {
            int hc = (n0 + wc*64 + n*16 + r) & 255;
            float bcol = bias[hc];
            #pragma unroll
            for (int m = 0; m < 2; ++m) {
                int row0 = m0 + wr*32 + m*16 + g*4;
                #pragma unroll
                for (int j = 0; j < 4; ++j) {
                    int rowj = row0 + j;
                    int t = rowj >> 5, rl = rowj & 31;
                    kb_t[(size_t)t*8192 + rl*256 + (((hc>>3) ^ (rl&7))*8) + (hc&7)]
                        = f2bf(acc[m][n][j] + bcol);
                }
            }
        }
    } else {
        #pragma unroll
        for (int n = 0; n < 4; ++n) {
            int hc = (n0 + wc*64 + n*16 + r) & 255;
            float bcol = bias[hc];
            #pragma unroll
            for (int m = 0; m < 2; ++m) {
                int kv0 = m0 + wr*32 + m*16 + g*4;
                int t = kv0 >> 5, kl = kv0 & 31;
                u16x4 pk;
                #pragma unroll
                for (int j = 0; j < 4; ++j) pk[j] = (short)f2bf(acc[m][n][j] + bcol);
                *(u16x4*)(vt_t + (size_t)t*8192 + hc*32 +
                          (((kl>>3) ^ (hc&3) ^ ((hc>>2)&3))*8) + (kl&7)) = pk;
            }
        }
    }
}

// ---------------------------------------------------------------------------
// Flash attention partial: block = 64 q-rows x chunk of C32 32-kv tiles.
// Wave w owns 16 q-rows (swapped-operand MFMA -> lane-local softmax, log2
// domain). gload_lds dbuf staging from pre-swizzled kb_t/vt_t, vmcnt(8),
// 2 raw barriers/tile, T13 defer-max, T5 setprio.
// ---------------------------------------------------------------------------
__global__ __launch_bounds__(256) void attn_part3(
    const u16* __restrict__ qb, const u16* __restrict__ kb_t,
    const u16* __restrict__ vt_t,
    float* __restrict__ po, float* __restrict__ pm, float* __restrict__ pl,
    int C32)
{
    __shared__ char Ks[2][16384];
    __shared__ char Vt[2][16384];
    __shared__ char Ps[4][1280];   // per wave [16 q][32 kv bf16], 80B rows

    const int qt = blockIdx.x;
    const int s  = blockIdx.y;
    const int nt = 2*qt + 2;
    const int ns = (nt + C32 - 1) / C32;
    if (s >= ns) return;
    int pid0 = 0;
    for (int k = 0; k < qt; ++k) pid0 += (2*k + 2 + C32 - 1) / C32;
    const int pid = pid0 + s;
    const int t0 = s * C32;
    const int t1 = min(t0 + C32, nt);

    const int tid = threadIdx.x;
    const int lane = tid & 63;
    const int w = tid >> 6;
    const int r = lane & 15, g = lane >> 4;
    const int qg = qt*64 + w*16 + r;

    // Q fragments (B-operand): lane r = q-row, slice g*8 + c*32
    bf16x8 qf[8];
    {
        const u16* qp = qb + (size_t)qg*HD + g*8;
        #pragma unroll
        for (int c = 0; c < 8; ++c) qf[c] = *(const bf16x8*)(qp + c*32);
    }
    VMCNT(0);   // drain q loads so counted vmcnt below sees only gload_lds

    auto stage = [&](int b, int t) {
        const u16* kg = kb_t + (size_t)t*8192 + w*2048 + lane*8;
        const u16* vg = vt_t + (size_t)t*8192 + w*2048 + lane*8;
        char* kl = Ks[b] + w*4096;
        char* vl = Vt[b] + w*4096;
        #pragma unroll
        for (int i = 0; i < 4; ++i) gl16(kg + i*512, kl + i*1024);
        #pragma unroll
        for (int i = 0; i < 4; ++i) gl16(vg + i*512, vl + i*1024);
    };

    stage(0, t0);
    if (t0 + 1 < t1) stage(1, t0 + 1);

    f32x4 zero = {0.f,0.f,0.f,0.f};
    f32x4 o[16];
    #pragma unroll
    for (int hf = 0; hf < 16; ++hf) o[hf] = zero;
    float mrun = -__builtin_inff(), lrun = 0.f;
    char* Psw = Ps[w];

    for (int t = t0; t < t1; ++t) {
        if (t + 1 < t1) { VMCNT(8); } else { VMCNT(0); }
        BAR();
        const char* K = Ks[t & 1];
        const char* V = Vt[t & 1];

        // ---- S^T = K Q^T : sv[f][j] = S[q=r][kv = t*32 + f*16 + g*4 + j]
        f32x4 sv[2];
        __builtin_amdgcn_s_setprio(1);
        #pragma unroll
        for (int f = 0; f < 2; ++f) {
            sv[f] = zero;
            int kv = f*16 + r;
            #pragma unroll
            for (int c = 0; c < 8; ++c) {
                bf16x8 kf = *(const bf16x8*)(K + kv*512 + (((c*4+g) ^ (kv&7)) << 4));
                sv[f] = __builtin_amdgcn_mfma_f32_16x16x32_bf16(kf, qf[c], sv[f], 0, 0, 0);
            }
        }
        __builtin_amdgcn_s_setprio(0);

        // ---- causal mask (log2-domain scores) ----
        if (t*32 + 31 > qg) {
            #pragma unroll
            for (int f = 0; f < 2; ++f)
                #pragma unroll
                for (int j = 0; j < 4; ++j)
                    if (t*32 + f*16 + g*4 + j > qg) sv[f][j] = -__builtin_inff();
        }

        // ---- lane-local online softmax with defer-max (T13, THR=8) ----
        float mx = fmaxf(fmaxf(fmaxf(sv[0][0], sv[0][1]), fmaxf(sv[0][2], sv[0][3])),
                         fmaxf(fmaxf(sv[1][0], sv[1][1]), fmaxf(sv[1][2], sv[1][3])));
        mx = fmaxf(mx, __shfl_xor(mx, 16));
        mx = fmaxf(mx, __shfl_xor(mx, 32));
        if (__any(mx > mrun + 8.0f)) {
            float mnew  = fmaxf(mrun, mx);
            float alpha = exp2f(mrun - mnew);
            lrun *= alpha;
            #pragma unroll
            for (int hf = 0; hf < 16; ++hf) o[hf] *= alpha;
            mrun = mnew;
        }
        float rs = 0.f;
        #pragma unroll
        for (int f = 0; f < 2; ++f)
            #pragma unroll
            for (int j = 0; j < 4; ++j) {
                float p = exp2f(sv[f][j] - mrun);
                sv[f][j] = p;
                rs += p;
            }
        rs += __shfl_xor(rs, 16);
        rs += __shfl_xor(rs, 32);
        lrun += rs;

        // ---- P -> bf16 -> wave-local Ps (no barrier) ----
        #pragma unroll
        for (int f = 0; f < 2; ++f)
            #pragma unroll
            for (int i2 = 0; i2 < 2; ++i2) {
                u32 pk = (u32)f2bf(sv[f][2*i2]) | ((u32)f2bf(sv[f][2*i2+1]) << 16);
                *(u32*)(Psw + r*80 + f*32 + g*8 + i2*4) = pk;
            }
        bf16x8 pa = *(const bf16x8*)(Psw + r*80 + g*16);

        // ---- O^T += V^T P^T ----
        __builtin_amdgcn_s_setprio(1);
        #pragma unroll
        for (int hf = 0; hf < 16; ++hf) {
            int hd = hf*16 + r;
            bf16x8 vf = *(const bf16x8*)(V + hd*64 + ((g ^ (r&3) ^ ((r>>2)&3)) << 4));
            o[hf] = __builtin_amdgcn_mfma_f32_16x16x32_bf16(vf, pa, o[hf], 0, 0, 0);
        }
        __builtin_amdgcn_s_setprio(0);

        BAR();
        if (t + 2 < t1) stage(t & 1, t + 2);
    }

    if (g == 0) {
        pm[(size_t)pid*64 + w*16 + r] = mrun;
        pl[(size_t)pid*64 + w*16 + r] = lrun;
    }
    float* op = po + ((size_t)pid*64 + w*16 + r) * 256;
    #pragma unroll
    for (int hf = 0; hf < 16; ++hf)
        *(f32x4*)(op + hf*16 + g*4) = o[hf];
}

// ---------------------------------------------------------------------------
// Combine split partials (log2-domain m).
// ---------------------------------------------------------------------------
__global__ __launch_bounds__(256) void attn_combine3(
    const float* __restrict__ po, const float* __restrict__ pm,
    const float* __restrict__ pl, float* __restrict__ out, int C32)
{
    const int tid = threadIdx.x;
    const int row = blockIdx.x * 16 + (tid >> 4);
    const int cg  = tid & 15;
    const int qt  = row >> 6, rr = row & 63;
    const int nt  = 2*qt + 2;
    const int ns  = (nt + C32 - 1) / C32;
    int pid0 = 0;
    for (int k = 0; k < qt; ++k) pid0 += (2*k + 2 + C32 - 1) / C32;

    float M = -__builtin_inff();
    for (int s = 0; s < ns; ++s)
        M = fmaxf(M, pm[(size_t)(pid0+s)*64 + rr]);

    float lt = 0.f;
    f32x4 acc[4];
    f32x4 zero = {0.f,0.f,0.f,0.f};
    #pragma unroll
    for (int v = 0; v < 4; ++v) acc[v] = zero;

    for (int s = 0; s < ns; ++s) {
        float ms  = pm[(size_t)(pid0+s)*64 + rr];
        float wgt = exp2f(ms - M);
        lt += wgt * pl[(size_t)(pid0+s)*64 + rr];
        const f32x4* p = (const f32x4*)(po + ((size_t)(pid0+s)*64 + rr)*256 + cg*16);
        #pragma unroll
        for (int v = 0; v < 4; ++v) acc[v] += p[v] * wgt;
    }
    float inv = 1.f / lt;
    f32x4* op = (f32x4*)(out + (size_t)row*256 + cg*16);
    #pragma unroll
    for (int v = 0; v < 4; ++v) op[v] = acc[v] * inv;
}

extern "C" void kernel_launch(void* const* d_in, const int* in_sizes, int n_in,
                              void* d_out, int out_size, void* d_ws, size_t ws_size,
                              hipStream_t stream) {
    const float* x  = (const float*)d_in[0];
    const float* Wq = (const float*)d_in[1];
    const float* bq = (const float*)d_in[2];
    const float* Wk = (const float*)d_in[3];
    const float* bk = (const float*)d_in[4];
    const float* Wv = (const float*)d_in[5];
    const float* bv = (const float*)d_in[6];
    float* out = (float*)d_out;

    const size_t xb_bytes  = (size_t)SEQ * DIMK * 2;   // 16 MB
    const size_t wb_bytes  = (size_t)768 * DIMK * 2;   // 3 MB
    const size_t qkv_bytes = (size_t)SEQ * HD * 2;     // 2 MB each
    const size_t base = xb_bytes + wb_bytes + 3*qkv_bytes;

    // pick split chunk C32 (32-kv tiles per block)
    int C32 = 64;
    size_t npid = 0;
    const int cand[4] = {8, 16, 32, 64};
    for (int ci = 0; ci < 4; ++ci) {
        int c = cand[ci];
        size_t np = 0;
        for (int qt = 0; qt < 64; ++qt) np += (size_t)(2*qt + 2 + c - 1) / c;
        size_t need = base + np * (64*256*4 + 2*64*4);
        if (need <= ws_size) { C32 = c; npid = np; break; }
        if (ci == 3) { C32 = c; npid = np; }
    }

    char* p = (char*)d_ws;
    u16* xb_sw = (u16*)p; p += xb_bytes;
    u16* wb_sw = (u16*)p; p += wb_bytes;
    u16* qbuf  = (u16*)p; p += qkv_bytes;
    u16* kb_t  = (u16*)p; p += qkv_bytes;
    u16* vt_t  = (u16*)p; p += qkv_bytes;
    float* po  = (float*)p; p += npid * 64 * 256 * 4;
    float* pm  = (float*)p; p += npid * 64 * 4;
    float* pl  = (float*)p; p += npid * 64 * 4;

    cvt_all2<<<dim3(512, 4), 256, 0, stream>>>(x, Wq, Wk, Wv, xb_sw, wb_sw);

    qkv_gemm2<<<dim3(SEQ/64, 6), 256, 0, stream>>>(
        xb_sw, wb_sw, bq, bk, bv, qbuf, kb_t, vt_t);

    const int maxns = (128 + C32 - 1) / C32;
    attn_part3<<<dim3(64, maxns), 256, 0, stream>>>(
        qbuf, kb_t, vt_t, po, pm, pl, C32);

    attn_combine3<<<SEQ/16, 256, 0, stream>>>(po, pm, pl, out, C32);
}

// Round 6
// 85.167 us; speedup vs baseline: 2.0019x; 1.0499x over previous
//
#include <hip/hip_runtime.h>
#include <stdint.h>

#define SEQ 4096
#define DIMK 2048
#define HD 256

typedef __attribute__((ext_vector_type(8))) short bf16x8;
typedef __attribute__((ext_vector_type(4))) short u16x4;
typedef __attribute__((ext_vector_type(4))) float f32x4;
typedef unsigned short u16;
typedef unsigned int u32;

#define BAR() asm volatile("s_barrier" ::: "memory")
#define VMCNT(n) asm volatile("s_waitcnt vmcnt(" #n ")" ::: "memory")

__device__ __forceinline__ u16 f2bf(float f) {
    u32 u = __float_as_uint(f);
    u += 0x7FFFu + ((u >> 16) & 1u);   // round-to-nearest-even
    return (u16)(u >> 16);
}

__device__ __forceinline__ float bf2f(u16 h) {
    u32 u = ((u32)h) << 16;
    return __uint_as_float(u);
}

__device__ __forceinline__ bf16x8 pack8(f32x4 a0, f32x4 a1) {
    bf16x8 v8;
    v8[0]=(short)f2bf(a0[0]); v8[1]=(short)f2bf(a0[1]);
    v8[2]=(short)f2bf(a0[2]); v8[3]=(short)f2bf(a0[3]);
    v8[4]=(short)f2bf(a1[0]); v8[5]=(short)f2bf(a1[1]);
    v8[6]=(short)f2bf(a1[2]); v8[7]=(short)f2bf(a1[3]);
    return v8;
}

// async global->LDS, 16B per lane, LDS dest = uniform base + lane*16
__device__ __forceinline__ void gl16(const void* g, void* l) {
    __builtin_amdgcn_global_load_lds(
        (const __attribute__((address_space(1))) void*)g,
        (__attribute__((address_space(3))) void*)l, 16, 0, 0);
}

// ---------------------------------------------------------------------------
// f32 -> bf16 convert INTO PRE-SWIZZLED GEMM TILE IMAGES. (verified r5)
// ---------------------------------------------------------------------------
__global__ __launch_bounds__(256) void cvt_all2(
    const float* __restrict__ x, const float* __restrict__ Wq,
    const float* __restrict__ Wk, const float* __restrict__ Wv,
    u16* __restrict__ xb_sw, u16* __restrict__ wb_sw)
{
    const int y = blockIdx.y;
    int i = blockIdx.x * 256 + threadIdx.x;
    int stride = gridDim.x * 256;
    if (y == 0) {
        for (; i < SEQ*DIMK/8; i += stride) {
            int row = i >> 8, c8 = i & 255;
            f32x4 a0 = *(const f32x4*)(x + (size_t)row*DIMK + c8*8);
            f32x4 a1 = *(const f32x4*)(x + (size_t)row*DIMK + c8*8 + 4);
            int mt = row >> 6, rl = row & 63, kt = c8 >> 3, sl = c8 & 7;
            size_t dst = ((size_t)(mt*32 + kt))*4096 + rl*64 + ((sl ^ (rl&7))*8);
            *(bf16x8*)(xb_sw + dst) = pack8(a0, a1);
        }
    } else {
        const float* W = (y==1) ? Wq : (y==2) ? Wk : Wv;
        for (; i < HD*DIMK/8; i += stride) {
            int row = i >> 8, c8 = i & 255;
            f32x4 a0 = *(const f32x4*)(W + (size_t)row*DIMK + c8*8);
            f32x4 a1 = *(const f32x4*)(W + (size_t)row*DIMK + c8*8 + 4);
            int gr = (y-1)*256 + row;
            int nt = gr >> 7, rl = gr & 127, kt = c8 >> 3, sl = c8 & 7;
            size_t dst = ((size_t)(nt*32 + kt))*8192 + rl*64 + ((sl ^ (rl&7))*8);
            *(bf16x8*)(wb_sw + dst) = pack8(a0, a1);
        }
    }
}

// ---------------------------------------------------------------------------
// QKV GEMM (verified r5): gload_lds dbuf, counted vmcnt(6). Outputs:
//   z=0: qb row-major, scaled by log2(e)/sqrt(2048)
//   z=1: kb_t = per-32kv tile [32][512B] swizzled K image
//   z=2: vt_t = per-32kv tile [256hd][64B] swizzled V^T image
// ---------------------------------------------------------------------------
__global__ __launch_bounds__(256) void qkv_gemm2(
    const u16* __restrict__ xb_sw, const u16* __restrict__ wb_sw,
    const float* __restrict__ bq, const float* __restrict__ bk,
    const float* __restrict__ bv,
    u16* __restrict__ qb, u16* __restrict__ kb_t, u16* __restrict__ vt_t)
{
    __shared__ char T[2][24576];   // A 8KB @ +0, B 16KB @ +8192

    const int tid = threadIdx.x;
    const int lane = tid & 63;
    const int w = tid >> 6;
    const int r = lane & 15, g = lane >> 4;
    const int wr = w >> 1, wc = w & 1;
    const int mt = blockIdx.x;
    const int y  = blockIdx.y;          // 0..5
    const int z  = y >> 1;
    const float* bias = (z==0) ? bq : (z==1) ? bk : bv;

    const u16* abase = xb_sw + (size_t)mt*32*4096;
    const u16* bbase = wb_sw + (size_t)y*32*8192;

    f32x4 zero = {0.f,0.f,0.f,0.f};
    f32x4 acc[2][4];
    #pragma unroll
    for (int m = 0; m < 2; ++m)
        #pragma unroll
        for (int n = 0; n < 4; ++n) acc[m][n] = zero;

    auto stage = [&](int b, int kt) {
        const u16* ag = abase + (size_t)kt*4096 + w*1024 + lane*8;
        const u16* bg = bbase + (size_t)kt*8192 + w*2048 + lane*8;
        char* al = T[b] + w*2048;
        char* bl = T[b] + 8192 + w*4096;
        gl16(ag,        al);
        gl16(ag + 512,  al + 1024);
        gl16(bg,        bl);
        gl16(bg + 512,  bl + 1024);
        gl16(bg + 1024, bl + 2048);
        gl16(bg + 1536, bl + 3072);
    };

    stage(0, 0);
    stage(1, 1);

    for (int kt = 0; kt < 32; ++kt) {
        if (kt < 31) { VMCNT(6); } else { VMCNT(0); }
        BAR();
        const char* A = T[kt & 1];
        const char* B = T[kt & 1] + 8192;
        #pragma unroll
        for (int kc = 0; kc < 2; ++kc) {
            bf16x8 af[2], bfr[4];
            #pragma unroll
            for (int m = 0; m < 2; ++m) {
                int arow = wr*32 + m*16 + r;
                af[m] = *(const bf16x8*)(A + arow*128 + (((kc*4+g) ^ (arow&7)) << 4));
            }
            #pragma unroll
            for (int n = 0; n < 4; ++n) {
                int brow = wc*64 + n*16 + r;
                bfr[n] = *(const bf16x8*)(B + brow*128 + (((kc*4+g) ^ (brow&7)) << 4));
            }
            #pragma unroll
            for (int m = 0; m < 2; ++m)
                #pragma unroll
                for (int n = 0; n < 4; ++n)
                    acc[m][n] = __builtin_amdgcn_mfma_f32_16x16x32_bf16(
                        af[m], bfr[n], acc[m][n], 0, 0, 0);
        }
        BAR();
        if (kt + 2 < 32) stage(kt & 1, kt + 2);
    }

    const int m0 = mt*64, n0 = y*128;
    const float qs = 0.03187936f;   // log2(e)/sqrt(2048)
    if (z == 0) {
        #pragma unroll
        for (int n = 0; n < 4; ++n) {
            int hc = (n0 + wc*64 + n*16 + r) & 255;
            float bcol = bias[hc];
            #pragma unroll
            for (int m = 0; m < 2; ++m) {
                int row0 = m0 + wr*32 + m*16 + g*4;
                #pragma unroll
                for (int j = 0; j < 4; ++j)
                    qb[(size_t)(row0+j)*HD + hc] = f2bf((acc[m][n][j] + bcol) * qs);
            }
        }
    } else if (z == 1) {
        #pragma unroll
        for (int n = 0; n < 4; ++n) {
            int hc = (n0 + wc*64 + n*16 + r) & 255;
            float bcol = bias[hc];
            #pragma unroll
            for (int m = 0; m < 2; ++m) {
                int row0 = m0 + wr*32 + m*16 + g*4;
                #pragma unroll
                for (int j = 0; j < 4; ++j) {
                    int rowj = row0 + j;
                    int t = rowj >> 5, rl = rowj & 31;
                    kb_t[(size_t)t*8192 + rl*256 + (((hc>>3) ^ (rl&7))*8) + (hc&7)]
                        = f2bf(acc[m][n][j] + bcol);
                }
            }
        }
    } else {
        #pragma unroll
        for (int n = 0; n < 4; ++n) {
            int hc = (n0 + wc*64 + n*16 + r) & 255;
            float bcol = bias[hc];
            #pragma unroll
            for (int m = 0; m < 2; ++m) {
                int kv0 = m0 + wr*32 + m*16 + g*4;
                int t = kv0 >> 5, kl = kv0 & 31;
                u16x4 pk;
                #pragma unroll
                for (int j = 0; j < 4; ++j) pk[j] = (short)f2bf(acc[m][n][j] + bcol);
                *(u16x4*)(vt_t + (size_t)t*8192 + hc*32 +
                          (((kl>>3) ^ (hc&3) ^ ((hc>>2)&3))*8) + (kl&7)) = pk;
            }
        }
    }
}

// ---------------------------------------------------------------------------
// Flash attention partial v2: flat grid of working units.
// Per tile: [vmcnt(4) gate][BAR][issue Vh(t) 2 gl16 + v0 8 reg loads][QK]
//           [vmcnt(8)][BAR][stage K(t+2) 4 gl16][softmax][PV0 regs][PV1 LDS]
// K: 2x16KB dbuf. Vh (hd 128..255): single 8KB in-tile buffer. Ps: 5KB.
// LDS 45KB -> 3 blocks/CU; launch_bounds(256,3) -> 12 waves/CU.
// ---------------------------------------------------------------------------
__global__ __launch_bounds__(256, 3) void attn_part4(
    const u16* __restrict__ qb, const u16* __restrict__ kb_t,
    const u16* __restrict__ vt_t,
    u16* __restrict__ po, float* __restrict__ pm, float* __restrict__ pl,
    int C32)
{
    __shared__ char Ks[2][16384];
    __shared__ char Vh[8192];
    __shared__ char Ps[4][1280];

    // decode flat pid -> (qt, s)
    const int pid = blockIdx.x;
    int qt = 0, acc0 = 0;
    for (int k = 0; k < 64; ++k) {
        int nsk = (2*k + 2 + C32 - 1) / C32;
        if (pid < acc0 + nsk) { qt = k; break; }
        acc0 += nsk;
    }
    const int s  = pid - acc0;
    const int nt = 2*qt + 2;
    const int t0 = s * C32;
    const int t1 = min(t0 + C32, nt);

    const int tid = threadIdx.x;
    const int lane = tid & 63;
    const int w = tid >> 6;
    const int r = lane & 15, g = lane >> 4;
    const int qg = qt*64 + w*16 + r;
    const int vswz = (g ^ (r&3) ^ ((r>>2)&3)) << 4;   // byte swizzle in 64B rows

    // Q fragments (B-operand): lane r = q-row, slice g*8 + c*32
    bf16x8 qf[8];
    {
        const u16* qp = qb + (size_t)qg*HD + g*8;
        #pragma unroll
        for (int c = 0; c < 8; ++c) qf[c] = *(const bf16x8*)(qp + c*32);
    }

    auto stageK = [&](int t, int buf) {
        const u16* kg = kb_t + (size_t)t*8192 + w*2048 + lane*8;
        char* kl = Ks[buf] + w*4096;
        #pragma unroll
        for (int i = 0; i < 4; ++i) gl16(kg + i*512, kl + i*1024);
    };

    stageK(t0, 0);
    if (t0 + 1 < t1) stageK(t0 + 1, 1); else stageK(t0, 1);

    f32x4 zero = {0.f,0.f,0.f,0.f};
    f32x4 o[16];
    #pragma unroll
    for (int hf = 0; hf < 16; ++hf) o[hf] = zero;
    float mrun = -__builtin_inff(), lrun = 0.f;
    char* Psw = Ps[w];

    for (int t = t0; t < t1; ++t) {
        VMCNT(4);          // K(t) landed (own wave's quarter)
        BAR();             // all quarters visible; prev-tile PV1 readers done
        const char* K = Ks[t & 1];

        // ---- issue Vh(t) (hd 128..255 half-tile) into LDS ----
        {
            const u16* vg = vt_t + (size_t)t*8192 + 4096 + w*1024 + lane*8;
            char* vl = Vh + w*2048;
            gl16(vg,       vl);
            gl16(vg + 512, vl + 1024);
        }
        // ---- issue v0 regs (hd 0..127 A-frags) direct from swizzled image ----
        bf16x8 v0[8];
        {
            const u16* vb = vt_t + (size_t)t*8192 + (size_t)r*32;
            #pragma unroll
            for (int hf = 0; hf < 8; ++hf)
                v0[hf] = *(const bf16x8*)((const char*)(vb + (size_t)hf*16*32) + vswz);
        }

        // ---- S^T = K Q^T : sv[f][j] = S[q=r][kv = t*32 + f*16 + g*4 + j]
        f32x4 sv[2];
        __builtin_amdgcn_s_setprio(1);
        #pragma unroll
        for (int f = 0; f < 2; ++f) {
            sv[f] = zero;
            int kv = f*16 + r;
            #pragma unroll
            for (int c = 0; c < 8; ++c) {
                bf16x8 kf = *(const bf16x8*)(K + kv*512 + (((c*4+g) ^ (kv&7)) << 4));
                sv[f] = __builtin_amdgcn_mfma_f32_16x16x32_bf16(kf, qf[c], sv[f], 0, 0, 0);
            }
        }
        __builtin_amdgcn_s_setprio(0);

        VMCNT(8);          // Vh(t) landed (own quarter); v0 still in flight
        BAR();             // Vh visible to all; all waves done reading Ks[t&1]

        // ---- stage K(t+2) into the buffer just freed (uniform counts) ----
        stageK(min(t + 2, t1 - 1), t & 1);

        // ---- causal mask ----
        if (t*32 + 31 > qg) {
            #pragma unroll
            for (int f = 0; f < 2; ++f)
                #pragma unroll
                for (int j = 0; j < 4; ++j)
                    if (t*32 + f*16 + g*4 + j > qg) sv[f][j] = -__builtin_inff();
        }

        // ---- lane-local online softmax, defer-max (T13, log2 domain) ----
        float mx = fmaxf(fmaxf(fmaxf(sv[0][0], sv[0][1]), fmaxf(sv[0][2], sv[0][3])),
                         fmaxf(fmaxf(sv[1][0], sv[1][1]), fmaxf(sv[1][2], sv[1][3])));
        mx = fmaxf(mx, __shfl_xor(mx, 16));
        mx = fmaxf(mx, __shfl_xor(mx, 32));
        if (__any(mx > mrun + 8.0f)) {
            float mnew  = fmaxf(mrun, mx);
            float alpha = exp2f(mrun - mnew);
            lrun *= alpha;
            #pragma unroll
            for (int hf = 0; hf < 16; ++hf) o[hf] *= alpha;
            mrun = mnew;
        }
        float rs = 0.f;
        #pragma unroll
        for (int f = 0; f < 2; ++f)
            #pragma unroll
            for (int j = 0; j < 4; ++j) {
                float p = exp2f(sv[f][j] - mrun);
                sv[f][j] = p;
                rs += p;
            }
        rs += __shfl_xor(rs, 16);
        rs += __shfl_xor(rs, 32);
        lrun += rs;

        // ---- P -> bf16 -> wave-local Ps (no barrier) ----
        #pragma unroll
        for (int f = 0; f < 2; ++f)
            #pragma unroll
            for (int i2 = 0; i2 < 2; ++i2) {
                u32 pk = (u32)f2bf(sv[f][2*i2]) | ((u32)f2bf(sv[f][2*i2+1]) << 16);
                *(u32*)(Psw + r*80 + f*32 + g*8 + i2*4) = pk;
            }
        bf16x8 pa = *(const bf16x8*)(Psw + r*80 + g*16);

        // ---- PV0: hd 0..127 from v0 regs (compiler waits vmcnt) ----
        __builtin_amdgcn_s_setprio(1);
        #pragma unroll
        for (int hf = 0; hf < 8; ++hf)
            o[hf] = __builtin_amdgcn_mfma_f32_16x16x32_bf16(v0[hf], pa, o[hf], 0, 0, 0);
        // ---- PV1: hd 128..255 from Vh LDS ----
        #pragma unroll
        for (int hf = 8; hf < 16; ++hf) {
            int lr = (hf-8)*16 + r;
            bf16x8 vf = *(const bf16x8*)(Vh + lr*64 + vswz);
            o[hf] = __builtin_amdgcn_mfma_f32_16x16x32_bf16(vf, pa, o[hf], 0, 0, 0);
        }
        __builtin_amdgcn_s_setprio(0);
    }

    VMCNT(0);   // drain outstanding DMA before LDS dealloc / exit

    if (g == 0) {
        pm[(size_t)pid*64 + w*16 + r] = mrun;
        pl[(size_t)pid*64 + w*16 + r] = lrun;
    }
    u16* op = po + ((size_t)pid*64 + w*16 + r) * 256;
    #pragma unroll
    for (int hf = 0; hf < 16; ++hf) {
        u16x4 pk;
        #pragma unroll
        for (int j = 0; j < 4; ++j) pk[j] = (short)f2bf(o[hf][j]);
        *(u16x4*)(op + hf*16 + g*4) = pk;
    }
}

// ---------------------------------------------------------------------------
// Combine split partials (bf16 po, log2-domain m).
// ---------------------------------------------------------------------------
__global__ __launch_bounds__(256) void attn_combine4(
    const u16* __restrict__ po, const float* __restrict__ pm,
    const float* __restrict__ pl, float* __restrict__ out, int C32)
{
    const int tid = threadIdx.x;
    const int row = blockIdx.x * 16 + (tid >> 4);
    const int cg  = tid & 15;
    const int qt  = row >> 6, rr = row & 63;
    const int nt  = 2*qt + 2;
    const int ns  = (nt + C32 - 1) / C32;
    int pid0 = 0;
    for (int k = 0; k < qt; ++k) pid0 += (2*k + 2 + C32 - 1) / C32;

    float M = -__builtin_inff();
    for (int s = 0; s < ns; ++s)
        M = fmaxf(M, pm[(size_t)(pid0+s)*64 + rr]);

    float lt = 0.f;
    f32x4 acc[4];
    f32x4 zero = {0.f,0.f,0.f,0.f};
    #pragma unroll
    for (int v = 0; v < 4; ++v) acc[v] = zero;

    for (int s = 0; s < ns; ++s) {
        float ms  = pm[(size_t)(pid0+s)*64 + rr];
        float wgt = exp2f(ms - M);
        lt += wgt * pl[(size_t)(pid0+s)*64 + rr];
        const u16* p = po + ((size_t)(pid0+s)*64 + rr)*256 + cg*16;
        #pragma unroll
        for (int v = 0; v < 4; ++v) {
            u16x4 pv = *(const u16x4*)(p + v*4);
            #pragma unroll
            for (int e = 0; e < 4; ++e)
                acc[v][e] += wgt * bf2f((u16)pv[e]);
        }
    }
    float inv = 1.f / lt;
    f32x4* op = (f32x4*)(out + (size_t)row*256 + cg*16);
    #pragma unroll
    for (int v = 0; v < 4; ++v) op[v] = acc[v] * inv;
}

extern "C" void kernel_launch(void* const* d_in, const int* in_sizes, int n_in,
                              void* d_out, int out_size, void* d_ws, size_t ws_size,
                              hipStream_t stream) {
    const float* x  = (const float*)d_in[0];
    const float* Wq = (const float*)d_in[1];
    const float* bq = (const float*)d_in[2];
    const float* Wk = (const float*)d_in[3];
    const float* bk = (const float*)d_in[4];
    const float* Wv = (const float*)d_in[5];
    const float* bv = (const float*)d_in[6];
    float* out = (float*)d_out;

    const size_t xb_bytes  = (size_t)SEQ * DIMK * 2;   // 16 MB
    const size_t wb_bytes  = (size_t)768 * DIMK * 2;   // 3 MB
    const size_t qkv_bytes = (size_t)SEQ * HD * 2;     // 2 MB each
    const size_t base = xb_bytes + wb_bytes + 3*qkv_bytes;

    // pick split chunk C32 (32-kv tiles per block): prefer 8
    int C32 = 64;
    size_t npid = 0;
    const int cand[4] = {8, 16, 32, 64};
    for (int ci = 0; ci < 4; ++ci) {
        int c = cand[ci];
        size_t np = 0;
        for (int qt = 0; qt < 64; ++qt) np += (size_t)(2*qt + 2 + c - 1) / c;
        size_t need = base + np * ((size_t)64*256*2 + 2*64*4);
        if (need <= ws_size) { C32 = c; npid = np; break; }
        if (ci == 3) { C32 = c; npid = np; }
    }

    char* p = (char*)d_ws;
    u16* xb_sw = (u16*)p; p += xb_bytes;
    u16* wb_sw = (u16*)p; p += wb_bytes;
    u16* qbuf  = (u16*)p; p += qkv_bytes;
    u16* kb_t  = (u16*)p; p += qkv_bytes;
    u16* vt_t  = (u16*)p; p += qkv_bytes;
    u16* po    = (u16*)p; p += npid * 64 * 256 * 2;
    float* pm  = (float*)p; p += npid * 64 * 4;
    float* pl  = (float*)p; p += npid * 64 * 4;

    cvt_all2<<<dim3(512, 4), 256, 0, stream>>>(x, Wq, Wk, Wv, xb_sw, wb_sw);

    qkv_gemm2<<<dim3(SEQ/64, 6), 256, 0, stream>>>(
        xb_sw, wb_sw, bq, bk, bv, qbuf, kb_t, vt_t);

    attn_part4<<<(int)npid, 256, 0, stream>>>(
        qbuf, kb_t, vt_t, po, pm, pl, C32);

    attn_combine4<<<SEQ/16, 256, 0, stream>>>(po, pm, pl, out, C32);
}